// Round 6
// baseline (8296.252 us; speedup 1.0000x reference)
//
#include <hip/hip_runtime.h>
#include <stdint.h>
#include <cstddef>

// ---------------------------------------------------------------------------
// GraphRNN-style generator. 2081 strictly-sequential GRU states distributed
// across 16 worker WGs (h sliced 16 elems, Whh LDS-resident), 1 classifier WG,
// 12 helper WGs (speculative Wih@h1). R6: the 29-WG cluster self-elects onto
// ONE physical XCD (HW_REG_XCC_ID + per-XCD tickets; first XCD to fill 29
// slots CAS-claims `winner`). Cross-WG words are DUAL-PUBLISHED (agent-scope
// store -> MALL, guaranteed-visible; plus sc0 store -> shared XCD L2) and
// consumed by capped sc0 polls (L2 latency ~250cy) with agent-poll fallback.
// Deadlock-free in every world: winner guaranteed (dead-man marker by block 0
// -> blockIdx-role agent-mode fallback), capped sc0 polls always degrade to
// agent polls, duplicate role computation writes identical values.
// Sentinel protocol: 0xFFFFFFFF (unreachable from finite f32 math).
// ---------------------------------------------------------------------------

#define H 256
#define HL 128
#define G3 768
#define NW 16
#define SL 16                       // H / NW
#define MAXN 64
#define NSTATE (1 + MAXN + (MAXN*(MAXN-1))/2)   // 2081
#define SENTU 0xFFFFFFFFu
#define DEADV 0x0000DEADu
#define PAD 264

#define WG_CLS NW                   // role 16
#define WG_HELP0 (NW+1)             // roles 17..28
#define NHELP_PER 6
#define NROLE (WG_HELP0 + 2*NHELP_PER) // 29
#define NWG 256                     // 1 WG/CU (LDS-forced); election picks 29

// output layout (f32 words), total 20928
#define NP_OFF 0
#define NI_OFF 192
#define NV_OFF 384
#define EP_OFF 448
#define EI_OFF (EP_OFF + MAXN*MAXN*2)   // 8640
#define EV_OFF (EI_OFF + MAXN*MAXN*2)   // 16832

struct Wksp {
  float h[NSTATE][H];          // hidden-state history (write-once words)
  float gi_e[MAXN][G3];        // eWih @ h1_i (speculative, no bias)
  float gi_n[MAXN][G3];        // nWih @ h1_i
  unsigned int dec[MAXN];      // 1 | is_end<<1 | no_edges<<2
  unsigned int winner;         // 0xFF-init; xcd id or DEADV
  unsigned int padw[7];
  // ---- zero-initialized region below ----
  unsigned int ticket[8];      // per-XCD election counters
};

union Shm {
  struct {
    float whe[3*SL*PAD];
    float whn[3*SL*PAD];
    float hcur[2][H];          // parity-double-buffered gathered state
    float bihe[3*SL], bhhe[3*SL], bihn[3*SL], bhhn[3*SL];
    float zv[HL];
    unsigned int dec;
  } w;
  struct {
    float cw[30*H];
    float cb[30];
    float hc[H];
    float logits[30];
    float resp[5];
    int   resi[5];
    float ept[MAXN][2];
    int   eit[MAXN][2];
  } c;
  struct { float h1[H]; } hp;
};

// ---- communication primitives --------------------------------------------
__device__ __forceinline__ unsigned int ld_sc0(const unsigned int* p) {
  unsigned int v;
  asm volatile("global_load_dword %0, %1, off sc0\n\ts_waitcnt vmcnt(0)"
               : "=&v"(v) : "v"(p) : "memory");
  return v;
}
__device__ __forceinline__ void st_sc0(unsigned int* p, unsigned int v) {
  asm volatile("global_store_dword %0, %1, off sc0" :: "v"(p), "v"(v) : "memory");
}
__device__ __forceinline__ unsigned int ld_ag(const unsigned int* p) {
  return __hip_atomic_load(p, __ATOMIC_RELAXED, __HIP_MEMORY_SCOPE_AGENT);
}
__device__ __forceinline__ void pub_u(unsigned int* p, unsigned int v) {
  __hip_atomic_store(p, v, __ATOMIC_RELAXED, __HIP_MEMORY_SCOPE_AGENT); // MALL
  st_sc0(p, v);                                                         // local L2
}
__device__ __forceinline__ void pubf(float* p, float x) {
  pub_u((unsigned int*)p, __float_as_uint(x));
}
__device__ __forceinline__ unsigned int spin_u(const unsigned int* p, bool sc) {
  unsigned int v;
  if (sc) {
    int tries = 0;
    v = ld_sc0(p);
    while (v == SENTU && ++tries < 8) v = ld_sc0(p);
  } else v = ld_ag(p);
  while (v == SENTU) v = ld_ag(p);
  return v;
}
__device__ __forceinline__ float spinf(const float* p, bool sc) {
  return __uint_as_float(spin_u((const unsigned int*)p, sc));
}
__device__ __forceinline__ float sigm(float x) { return 1.0f / (1.0f + expf(-x)); }

__global__ __launch_bounds__(256)
void Generator_34746285425383_kernel(
    const float* __restrict__ z, const float* __restrict__ lp_w, const float* __restrict__ lp_b,
    const float* __restrict__ nWih, const float* __restrict__ nWhh,
    const float* __restrict__ nbih, const float* __restrict__ nbhh,
    const float* __restrict__ eWih, const float* __restrict__ eWhh,
    const float* __restrict__ ebih, const float* __restrict__ ebhh,
    const float* __restrict__ nc0w, const float* __restrict__ nc0b,
    const float* __restrict__ nc1w, const float* __restrict__ nc1b,
    const float* __restrict__ nc2w, const float* __restrict__ nc2b,
    const float* __restrict__ ec0w, const float* __restrict__ ec0b,
    const float* __restrict__ ec1w, const float* __restrict__ ec1b,
    float* __restrict__ out, Wksp* __restrict__ ws)
{
  __shared__ Shm S;
  __shared__ int role_s, mode_s;
  const int tid = threadIdx.x;

  // ---------------- election: form the 29-role cluster on ONE XCD ---------
  if (tid == 0) {
    unsigned int xcc;
    asm volatile("s_getreg_b32 %0, hwreg(HW_REG_XCC_ID)" : "=s"(xcc));
    xcc &= 7u;
    const unsigned int slot = __hip_atomic_fetch_add(&ws->ticket[xcc], 1u,
                                __ATOMIC_RELAXED, __HIP_MEMORY_SCOPE_AGENT);
    if (slot == NROLE - 1) {                  // my XCD just completed a 29-set
      unsigned int exp = SENTU;
      __hip_atomic_compare_exchange_strong(&ws->winner, &exp, xcc,
          __ATOMIC_RELAXED, __ATOMIC_RELAXED, __HIP_MEMORY_SCOPE_AGENT);
    }
    unsigned int wv = ld_ag(&ws->winner);
    int iters = 0;
    while (wv == SENTU) {                     // guaranteed bounded (dead-man)
      ++iters;
      if (iters > 1500 && blockIdx.x == 0) {
        unsigned int exp = SENTU;
        __hip_atomic_compare_exchange_strong(&ws->winner, &exp, DEADV,
            __ATOMIC_RELAXED, __ATOMIC_RELAXED, __HIP_MEMORY_SCOPE_AGENT);
      }
      wv = ld_ag(&ws->winner);
    }
    if (wv <= 7u) {                           // real winner XCD
      role_s = (wv == xcc && slot < NROLE) ? (int)slot : -1;
      mode_s = 1;                             // sc0 fast path enabled
    } else {                                  // DEADV: fallback, agent-only
      role_s = ((int)blockIdx.x < NROLE) ? (int)blockIdx.x : -1;
      mode_s = 0;
    }
  }
  __syncthreads();
  const int bid = role_s;
  const bool sc = (mode_s != 0);
  if (bid < 0) return;

  if (bid < NW) {
    // =================== WORKER ===================
    const int w = bid, g = tid >> 4, c = tid & 15;
    const int k = w * SL + g;
    for (int r = 0; r < 3 * SL; ++r) {
      const int gate = r / SL, gg = r % SL;
      const int grow = gate * H + (w * SL + gg);
      for (int col = tid; col < H; col += 256) {
        S.w.whe[r * PAD + col] = eWhh[grow * H + col];
        S.w.whn[r * PAD + col] = nWhh[grow * H + col];
      }
    }
    if (tid < 3 * SL) {
      const int gate = tid / SL, gg = tid % SL;
      const int grow = gate * H + w * SL + gg;
      S.w.bihe[tid] = ebih[grow]; S.w.bhhe[tid] = ebhh[grow];
      S.w.bihn[tid] = nbih[grow]; S.w.bhhn[tid] = nbhh[grow];
    }
    if (tid < HL) S.w.zv[tid] = z[tid];
    __syncthreads();

    // state 0: h0 = z @ lp_w.T + lp_b
    {
      float p = 0.f;
      for (int it = 0; it < 8; ++it) {
        const int col = c + 16 * it;
        p += S.w.zv[col] * lp_w[k * HL + col];
      }
      for (int off = 1; off < 16; off <<= 1) p += __shfl_xor(p, off);
      if (c == 0) pubf(&ws->h[0][k], p + lp_b[k]);
    }

    int m = 1, idx_carry = 0;
    bool done = false;
    unsigned long long valid = 0ull;
    float pg0 = 0.f, pg1 = 0.f, pg2 = 0.f;
    const float* pga = nullptr;

    for (int i = 0; i < MAXN; ++i) {
      for (int t = -1; t < i; ++t) {
        const bool is_node = (t < 0);
        const int hidx = is_node ? idx_carry : (m - 1);
        const int src  = is_node ? (i - 1) : (i - 1 - t);
        float* hc = S.w.hcur[m & 1];
        hc[tid] = spinf(&ws->h[hidx][tid], sc);
        float gi0 = 0.f, gi1 = 0.f, gi2 = 0.f;
        const bool use_gi = (src >= 0) && ((valid >> src) & 1ull);
        if (use_gi) {
          gi0 = pg0; gi1 = pg1; gi2 = pg2;
          if (__float_as_uint(gi0) == SENTU) gi0 = spinf(&pga[0 * H + k], sc);
          if (__float_as_uint(gi1) == SENTU) gi1 = spinf(&pga[1 * H + k], sc);
          if (__float_as_uint(gi2) == SENTU) gi2 = spinf(&pga[2 * H + k], sc);
        }
        __syncthreads();                      // the ONE barrier per state
        const float* Wl = is_node ? S.w.whn : S.w.whe;
        float p0 = 0.f, p1 = 0.f, p2 = 0.f;
        #pragma unroll
        for (int it = 0; it < 16; ++it) {
          const int col = c + 16 * it;
          const float hv = hc[col];
          p0 += Wl[(0 * SL + g) * PAD + col] * hv;
          p1 += Wl[(1 * SL + g) * PAD + col] * hv;
          p2 += Wl[(2 * SL + g) * PAD + col] * hv;
        }
        for (int off = 1; off < 16; off <<= 1) {
          p0 += __shfl_xor(p0, off);
          p1 += __shfl_xor(p1, off);
          p2 += __shfl_xor(p2, off);
        }
        const float* bih = is_node ? S.w.bihn : S.w.bihe;
        const float* bhh = is_node ? S.w.bhhn : S.w.bhhe;
        const float rr = sigm(gi0 + bih[0 * SL + g] + p0 + bhh[0 * SL + g]);
        const float zz = sigm(gi1 + bih[1 * SL + g] + p1 + bhh[1 * SL + g]);
        const float nn = tanhf(gi2 + bih[2 * SL + g] + rr * (p2 + bhh[2 * SL + g]));
        const float hp = (1.f - zz) * nn + zz * hc[k];
        if (c == 0) pubf(&ws->h[m][k], hp);
        {
          int ni = i, nt = t + 1;
          if (nt >= i) { ni = i + 1; nt = -1; }
          if (ni < MAXN) {
            const bool nnode = (nt < 0);
            const int nsrc = nnode ? (ni - 1) : (ni - 1 - nt);
            if (nsrc >= 0) {
              pga = nnode ? ws->gi_n[nsrc] : ws->gi_e[nsrc];
              pg0 = __builtin_nontemporal_load(&pga[0 * H + k]);
              pg1 = __builtin_nontemporal_load(&pga[1 * H + k]);
              pg2 = __builtin_nontemporal_load(&pga[2 * H + k]);
            }
          }
        }
        ++m;
      }
      // boundary: consume classifier decision
      if (tid == 0) S.w.dec = spin_u(&ws->dec[i], sc);
      __syncthreads();
      const unsigned int dec = S.w.dec;
      const bool is_end   = (dec >> 1) & 1u;
      const bool no_edges = (dec >> 2) & 1u;
      const bool active   = !done;
      const bool node_ok  = active && !is_end && !no_edges;
      if (node_ok) valid |= (1ull << i);
      const int s_end = m - 1, node_m = m - 1 - i;
      if (active) idx_carry = (node_ok && i > 0) ? s_end : node_m;
      done = done || is_end || no_edges;
    }

  } else if (bid == WG_CLS) {
    // =================== CLASSIFIER ===================
    const int g = tid >> 4, c = tid & 15;
    const float* wsrc[5] = { nc0w, nc1w, nc2w, ec0w, ec1w };
    const float* bsrc[5] = { nc0b, nc1b, nc2b, ec0b, ec1b };
    const int hbase[5] = { 0, 12, 17, 21, 26 };
    const int hlen[5]  = { 12, 5, 4, 5, 4 };
    for (int hh = 0; hh < 5; ++hh)
      for (int r = 0; r < hlen[hh]; ++r)
        for (int col = tid; col < H; col += 256)
          S.c.cw[(hbase[hh] + r) * H + col] = wsrc[hh][r * H + col];
    if (tid < 30) {
      const int hh = tid < 12 ? 0 : tid < 17 ? 1 : tid < 21 ? 2 : tid < 26 ? 3 : 4;
      S.c.cb[tid] = bsrc[hh][tid - hbase[hh]];
    }
    __syncthreads();

    int m = 1;
    bool done = false;
    for (int i = 0; i < MAXN; ++i) {
      float npmax[3]; int nidx[3];
      bool is_end = false, andacc = true;
      for (int t = -1; t < i; ++t) {
        S.c.hc[tid] = spinf(&ws->h[m][tid], sc);
        __syncthreads();
        for (int rsel = 0; rsel < 2; ++rsel) {
          const int r = g + 16 * rsel;
          float p = 0.f;
          if (r < 30) {
            #pragma unroll
            for (int it = 0; it < 16; ++it) {
              const int col = c + 16 * it;
              p += S.c.cw[r * H + col] * S.c.hc[col];
            }
          }
          for (int off = 1; off < 16; off <<= 1) p += __shfl_xor(p, off);
          if (r < 30 && c == 0) S.c.logits[r] = p + S.c.cb[r];
        }
        __syncthreads();
        if (tid < 5) {
          const int base = hbase[tid], len = hlen[tid];
          float best = S.c.logits[base]; int bi = 0;
          for (int j = 1; j < len; ++j) {
            const float l = S.c.logits[base + j];
            if (l > best) { best = l; bi = j; }
          }
          float s = 0.f;
          for (int j = 0; j < len; ++j) s += expf(S.c.logits[base + j] - best);
          S.c.resp[tid] = 1.0f / s;
          S.c.resi[tid] = bi;
        }
        __syncthreads();
        if (t < 0) {
          npmax[0] = S.c.resp[0]; npmax[1] = S.c.resp[1]; npmax[2] = S.c.resp[2];
          nidx[0] = S.c.resi[0]; nidx[1] = S.c.resi[1]; nidx[2] = S.c.resi[2];
          is_end = (S.c.resi[0] == 11);            // END_NODE
          if (i == 0 && tid == 0) {
            S.c.ept[0][0] = S.c.resp[3]; S.c.ept[0][1] = S.c.resp[4];
            S.c.eit[0][0] = S.c.resi[3]; S.c.eit[0][1] = S.c.resi[4];
          }
        } else {
          if (tid == 0) {
            S.c.ept[t][0] = S.c.resp[3]; S.c.ept[t][1] = S.c.resp[4];
            S.c.eit[t][0] = S.c.resi[3]; S.c.eit[t][1] = S.c.resi[4];
          }
          andacc = andacc && (S.c.resi[3] == 0);
        }
        __syncthreads();
        ++m;
      }
      const bool no_edges = (i > 0) && andacc;
      const bool active = !done;
      const bool node_ok = active && !is_end && !no_edges;
      if (tid == 0)
        pub_u(&ws->dec[i], 1u | (is_end ? 2u : 0u) | (no_edges ? 4u : 0u));
      if (tid < MAXN) {
        const int j = tid;
        const bool vj = j < i;
        const bool ev = vj && node_ok && (i > 0);
        const int tt = vj ? (i - 1 - j) : 0;
        out[EP_OFF + (i * MAXN + j) * 2 + 0] = ev ? S.c.ept[tt][0] : 0.f;
        out[EP_OFF + (i * MAXN + j) * 2 + 1] = ev ? S.c.ept[tt][1] : 0.f;
        out[EI_OFF + (i * MAXN + j) * 2 + 0] = (float)S.c.eit[tt][0];
        out[EI_OFF + (i * MAXN + j) * 2 + 1] = (float)S.c.eit[tt][1];
        out[EV_OFF + i * MAXN + j] = ev ? 1.f : 0.f;
      } else if (tid < MAXN + 8) {
        const int q = tid - MAXN;
        if (q < 3)       out[NP_OFF + i * 3 + q]       = node_ok ? npmax[q] : 0.f;
        else if (q < 6)  out[NI_OFF + i * 3 + (q - 3)] = (float)nidx[q - 3];
        else if (q == 6) out[NV_OFF + i]               = node_ok ? 1.f : 0.f;
      }
      done = done || is_end || no_edges;
      __syncthreads();
    }

  } else {
    // =================== Gi HELPERS ===================
    const int e = bid - WG_HELP0;               // 0..11
    const bool is_edge = (e < NHELP_PER);
    const int rowbase = (e % NHELP_PER) * 128;
    const float* Wih = is_edge ? eWih : nWih;
    float* gdst = is_edge ? &ws->gi_e[0][0] : &ws->gi_n[0][0];
    const int g = tid >> 4, c = tid & 15;
    int m_node = 1;
    for (int i = 0; i < MAXN; ++i) {
      S.hp.h1[tid] = spinf(&ws->h[m_node][tid], sc);
      __syncthreads();
      for (int rr = 0; rr < 8; ++rr) {
        const int row = rowbase + g * 8 + rr;
        float p = 0.f;
        #pragma unroll
        for (int u = 0; u < 4; ++u) {
          const float4 wv = *(const float4*)&Wih[row * H + c * 16 + u * 4];
          p += wv.x * S.hp.h1[c * 16 + u * 4 + 0]
             + wv.y * S.hp.h1[c * 16 + u * 4 + 1]
             + wv.z * S.hp.h1[c * 16 + u * 4 + 2]
             + wv.w * S.hp.h1[c * 16 + u * 4 + 3];
        }
        for (int off = 1; off < 16; off <<= 1) p += __shfl_xor(p, off);
        if (c == 0) pubf(&gdst[i * G3 + row], p);
      }
      __syncthreads();
      m_node += 1 + i;
    }
  }
}

extern "C" void kernel_launch(void* const* d_in, const int* in_sizes, int n_in,
                              void* d_out, int out_size, void* d_ws, size_t ws_size,
                              hipStream_t stream) {
  // sentinel-fill comm region (incl. winner); zero the election tickets
  hipMemsetAsync(d_ws, 0xFF, offsetof(Wksp, ticket), stream);
  hipMemsetAsync((char*)d_ws + offsetof(Wksp, ticket), 0,
                 sizeof(Wksp) - offsetof(Wksp, ticket), stream);
  Generator_34746285425383_kernel<<<dim3(NWG), dim3(256), 0, stream>>>(
      (const float*)d_in[0],  (const float*)d_in[1],  (const float*)d_in[2],
      (const float*)d_in[3],  (const float*)d_in[4],  (const float*)d_in[5],
      (const float*)d_in[6],  (const float*)d_in[7],  (const float*)d_in[8],
      (const float*)d_in[9],  (const float*)d_in[10],
      (const float*)d_in[11], (const float*)d_in[12],
      (const float*)d_in[13], (const float*)d_in[14],
      (const float*)d_in[15], (const float*)d_in[16],
      (const float*)d_in[17], (const float*)d_in[18],
      (const float*)d_in[19], (const float*)d_in[20],
      (float*)d_out, (Wksp*)d_ws);
}

// Round 8
// 5274.899 us; speedup vs baseline: 1.5728x; 1.5728x over previous
//
#include <hip/hip_runtime.h>
#include <stdint.h>
#include <cstddef>

// ---------------------------------------------------------------------------
// GraphRNN-style generator. 2081 strictly-sequential GRU states across
// 16 worker WGs (h sliced 16 elems, Whh LDS-resident), 1 classifier WG,
// 12 helper WGs (speculative Wih@h1). R8 = R5 skeleton + R6's PROVEN pieces:
//  - 29-role cluster elected onto ONE XCD (HW_REG_XCC_ID ticket + CAS winner,
//    dead-man fallback to blockIdx roles/agent mode; ran hang-free in R6).
//  - h and dec are DUAL-COPY: primary written with sc0 store (lands in the
//    shared XCD L2, read by sc0 loads at ~300-500cy RT) and a SHADOW at a
//    DIFFERENT address written with agent-scope store (guaranteed visible).
//    Consumers: 16 capped sc0 polls on primary, then agent-spin the shadow.
//    Word-granular, sentinel-self-validating, deadlock-impossible.
//  - gi stays on the proven agent path (produced rounds ahead of use).
//  - heaters removed (R5 proved clocks are not the limiter).
// Sentinel: 0xFFFFFFFF (unreachable from finite f32 math), write-once words.
// ---------------------------------------------------------------------------

typedef unsigned int u32;

#define H 256
#define HL 128
#define G3 768
#define NW 16
#define SL 16
#define MAXN 64
#define NSTATE (1 + MAXN + (MAXN*(MAXN-1))/2)   // 2081
#define SENTU 0xFFFFFFFFu
#define DEADV 0x0000DEADu
#define PAD 264

#define WG_CLS NW                   // role 16
#define WG_HELP0 (NW+1)             // roles 17..28
#define NHELP_PER 6
#define NROLE (WG_HELP0 + 2*NHELP_PER) // 29  (<= 32 CUs per XCD)
#define NWG 256                     // 1 WG/CU (LDS-forced); election picks 29

// output layout (f32 words), total 20928
#define NP_OFF 0
#define NI_OFF 192
#define NV_OFF 384
#define EP_OFF 448
#define EI_OFF (EP_OFF + MAXN*MAXN*2)   // 8640
#define EV_OFF (EI_OFF + MAXN*MAXN*2)   // 16832

struct Wksp {
  float hP[NSTATE][H];         // primary h copies (sc0 domain)
  float hS[NSTATE][H];         // shadow h copies (agent domain)
  float gi_e[MAXN][G3];        // eWih @ h1_i (agent domain)
  float gi_n[MAXN][G3];        // nWih @ h1_i
  u32 decP[MAXN];              // primary dec
  u32 decS[MAXN];              // shadow dec
  u32 winner;                  // 0xFF-init; xcd id or DEADV
  u32 padw[7];
  // ---- zero-initialized region below ----
  u32 ticket[8];               // per-XCD election counters
};

union Shm {
  struct {
    float whe[3*SL*PAD];
    float whn[3*SL*PAD];
    float hcur[2][H];          // parity-double-buffered gathered state
    float bihe[3*SL], bhhe[3*SL], bihn[3*SL], bhhn[3*SL];
    float zv[HL];
    u32 dec;
  } w;
  struct {
    float cw[30*H];
    float cb[30];
    float hc[H];
    float logits[30];
    float resp[5];
    int   resi[5];
    float ept[MAXN][2];
    int   eit[MAXN][2];
  } c;
  struct { float h1[H]; } hp;
};

// ---- primitives -----------------------------------------------------------
__device__ __forceinline__ u32 ld_sc0(const u32* p) {
  u32 v;
  asm volatile("global_load_dword %0, %1, off sc0\n\ts_waitcnt vmcnt(0)"
               : "=&v"(v) : "v"(p) : "memory");
  return v;
}
__device__ __forceinline__ void st_sc0(u32* p, u32 v) {
  asm volatile("global_store_dword %0, %1, off sc0" :: "v"(p), "v"(v) : "memory");
}
__device__ __forceinline__ u32 ld_ag(const u32* p) {
  return __hip_atomic_load(p, __ATOMIC_RELAXED, __HIP_MEMORY_SCOPE_AGENT);
}
__device__ __forceinline__ void st_ag(u32* p, u32 v) {
  __hip_atomic_store(p, v, __ATOMIC_RELAXED, __HIP_MEMORY_SCOPE_AGENT);
}
// dual publish: primary (sc0, fast in-XCD) first, then shadow (agent, safe)
__device__ __forceinline__ void pub2(u32* pp, u32* sp, u32 v, bool sc) {
  if (sc) st_sc0(pp, v);
  st_ag(sp, v);
}
__device__ __forceinline__ void pub2f(float* pp, float* sp, float x, bool sc) {
  pub2((u32*)pp, (u32*)sp, __float_as_uint(x), sc);
}
// consume: capped sc0 polls on primary, then guaranteed agent spin on shadow
__device__ __forceinline__ u32 spin2(const u32* pp, const u32* sp, bool sc) {
  if (sc) {
    #pragma unroll 1
    for (int i = 0; i < 16; ++i) {
      const u32 v = ld_sc0(pp);
      if (v != SENTU) return v;
    }
  }
  u32 v = ld_ag(sp);
  while (v == SENTU) v = ld_ag(sp);
  return v;
}
__device__ __forceinline__ float spin2f(const float* pp, const float* sp, bool sc) {
  return __uint_as_float(spin2((const u32*)pp, (const u32*)sp, sc));
}
// agent-only helpers (gi path, helper WGs)
__device__ __forceinline__ float spinf(const float* p) {
  u32 v = ld_ag((const u32*)p);
  while (v == SENTU) v = ld_ag((const u32*)p);
  return __uint_as_float(v);
}
__device__ __forceinline__ void pubf(float* p, float x) { st_ag((u32*)p, __float_as_uint(x)); }
__device__ __forceinline__ float sigm(float x) { return 1.0f / (1.0f + expf(-x)); }

__global__ __launch_bounds__(256)
void Generator_34746285425383_kernel(
    const float* __restrict__ z, const float* __restrict__ lp_w, const float* __restrict__ lp_b,
    const float* __restrict__ nWih, const float* __restrict__ nWhh,
    const float* __restrict__ nbih, const float* __restrict__ nbhh,
    const float* __restrict__ eWih, const float* __restrict__ eWhh,
    const float* __restrict__ ebih, const float* __restrict__ ebhh,
    const float* __restrict__ nc0w, const float* __restrict__ nc0b,
    const float* __restrict__ nc1w, const float* __restrict__ nc1b,
    const float* __restrict__ nc2w, const float* __restrict__ nc2b,
    const float* __restrict__ ec0w, const float* __restrict__ ec0b,
    const float* __restrict__ ec1w, const float* __restrict__ ec1b,
    float* __restrict__ out, Wksp* __restrict__ ws)
{
  __shared__ Shm S;
  __shared__ int role_s, mode_s;
  const int tid = threadIdx.x;

  // ---------------- election (R6-proven): 29 roles on ONE XCD -------------
  if (tid == 0) {
    u32 xcc;
    asm volatile("s_getreg_b32 %0, hwreg(HW_REG_XCC_ID)" : "=s"(xcc));
    xcc &= 7u;
    const u32 slot = __hip_atomic_fetch_add(&ws->ticket[xcc], 1u,
                        __ATOMIC_RELAXED, __HIP_MEMORY_SCOPE_AGENT);
    if (slot == NROLE - 1) {
      u32 exp = SENTU;
      __hip_atomic_compare_exchange_strong(&ws->winner, &exp, xcc,
          __ATOMIC_RELAXED, __ATOMIC_RELAXED, __HIP_MEMORY_SCOPE_AGENT);
    }
    u32 wv = ld_ag(&ws->winner);
    int iters = 0;
    while (wv == SENTU) {
      ++iters;
      if (iters > 1500 && blockIdx.x == 0) {
        u32 exp = SENTU;
        __hip_atomic_compare_exchange_strong(&ws->winner, &exp, DEADV,
            __ATOMIC_RELAXED, __ATOMIC_RELAXED, __HIP_MEMORY_SCOPE_AGENT);
      }
      wv = ld_ag(&ws->winner);
    }
    if (wv <= 7u) { role_s = (wv == xcc && slot < NROLE) ? (int)slot : -1; mode_s = 1; }
    else          { role_s = ((int)blockIdx.x < NROLE) ? (int)blockIdx.x : -1; mode_s = 0; }
  }
  __syncthreads();
  const int bid = role_s;
  const bool sc = (mode_s != 0);
  if (bid < 0) return;

  if (bid < NW) {
    // =================== WORKER ===================
    const int w = bid, g = tid >> 4, c = tid & 15;
    const int k = w * SL + g;
    for (int r = 0; r < 3 * SL; ++r) {
      const int gate = r / SL, gg = r % SL;
      const int grow = gate * H + (w * SL + gg);
      for (int col = tid; col < H; col += 256) {
        S.w.whe[r * PAD + col] = eWhh[grow * H + col];
        S.w.whn[r * PAD + col] = nWhh[grow * H + col];
      }
    }
    if (tid < 3 * SL) {
      const int gate = tid / SL, gg = tid % SL;
      const int grow = gate * H + w * SL + gg;
      S.w.bihe[tid] = ebih[grow]; S.w.bhhe[tid] = ebhh[grow];
      S.w.bihn[tid] = nbih[grow]; S.w.bhhn[tid] = nbhh[grow];
    }
    if (tid < HL) S.w.zv[tid] = z[tid];
    __syncthreads();

    // state 0: h0 = z @ lp_w.T + lp_b
    {
      float p = 0.f;
      for (int it = 0; it < 8; ++it) {
        const int col = c + 16 * it;
        p += S.w.zv[col] * lp_w[k * HL + col];
      }
      for (int off = 1; off < 16; off <<= 1) p += __shfl_xor(p, off);
      if (c == 0) pub2f(&ws->hP[0][k], &ws->hS[0][k], p + lp_b[k], sc);
    }

    int m = 1, idx_carry = 0;
    bool done = false;
    unsigned long long valid = 0ull;
    float pg0 = 0.f, pg1 = 0.f, pg2 = 0.f;
    const float* pga = nullptr;

    for (int i = 0; i < MAXN; ++i) {
      for (int t = -1; t < i; ++t) {        // t=-1: node step, t>=0: edge steps
        const bool is_node = (t < 0);
        const int hidx = is_node ? idx_carry : (m - 1);
        const int src  = is_node ? (i - 1) : (i - 1 - t);
        float* hc = S.w.hcur[m & 1];
        hc[tid] = spin2f(&ws->hP[hidx][tid], &ws->hS[hidx][tid], sc);
        // x-side: consume prefetched gi words (sentinel -> agent respin)
        float gi0 = 0.f, gi1 = 0.f, gi2 = 0.f;
        const bool use_gi = (src >= 0) && ((valid >> src) & 1ull);
        if (use_gi) {
          gi0 = pg0; gi1 = pg1; gi2 = pg2;
          if (__float_as_uint(gi0) == SENTU) gi0 = spinf(&pga[0 * H + k]);
          if (__float_as_uint(gi1) == SENTU) gi1 = spinf(&pga[1 * H + k]);
          if (__float_as_uint(gi2) == SENTU) gi2 = spinf(&pga[2 * H + k]);
        }
        __syncthreads();                    // the ONE barrier per state
        const float* Wl = is_node ? S.w.whn : S.w.whe;
        float p0 = 0.f, p1 = 0.f, p2 = 0.f;
        #pragma unroll
        for (int it = 0; it < 16; ++it) {
          const int col = c + 16 * it;
          const float hv = hc[col];
          p0 += Wl[(0 * SL + g) * PAD + col] * hv;
          p1 += Wl[(1 * SL + g) * PAD + col] * hv;
          p2 += Wl[(2 * SL + g) * PAD + col] * hv;
        }
        for (int off = 1; off < 16; off <<= 1) {
          p0 += __shfl_xor(p0, off);
          p1 += __shfl_xor(p1, off);
          p2 += __shfl_xor(p2, off);
        }
        const float* bih = is_node ? S.w.bihn : S.w.bihe;
        const float* bhh = is_node ? S.w.bhhn : S.w.bhhe;
        const float rr = sigm(gi0 + bih[0 * SL + g] + p0 + bhh[0 * SL + g]);
        const float zz = sigm(gi1 + bih[1 * SL + g] + p1 + bhh[1 * SL + g]);
        const float nn = tanhf(gi2 + bih[2 * SL + g] + rr * (p2 + bhh[2 * SL + g]));
        const float hp = (1.f - zz) * nn + zz * hc[k];
        if (c == 0) pub2f(&ws->hP[m][k], &ws->hS[m][k], hp, sc);
        // prefetch next state's gi words (agent path; overlaps next spin)
        {
          int ni = i, nt = t + 1;
          if (nt >= i) { ni = i + 1; nt = -1; }
          if (ni < MAXN) {
            const bool nnode = (nt < 0);
            const int nsrc = nnode ? (ni - 1) : (ni - 1 - nt);
            if (nsrc >= 0) {
              pga = nnode ? ws->gi_n[nsrc] : ws->gi_e[nsrc];
              pg0 = __builtin_nontemporal_load(&pga[0 * H + k]);
              pg1 = __builtin_nontemporal_load(&pga[1 * H + k]);
              pg2 = __builtin_nontemporal_load(&pga[2 * H + k]);
            }
          }
        }
        ++m;                                // parity buffers: no trailing barrier
      }
      // boundary: consume classifier decision
      if (tid == 0) S.w.dec = spin2(&ws->decP[i], &ws->decS[i], sc);
      __syncthreads();
      const u32 dec = S.w.dec;
      const bool is_end   = (dec >> 1) & 1u;
      const bool no_edges = (dec >> 2) & 1u;
      const bool active   = !done;
      const bool node_ok  = active && !is_end && !no_edges;
      if (node_ok) valid |= (1ull << i);
      const int s_end = m - 1, node_m = m - 1 - i;
      if (active) idx_carry = (node_ok && i > 0) ? s_end : node_m;
      done = done || is_end || no_edges;
    }

  } else if (bid == WG_CLS) {
    // =================== CLASSIFIER ===================
    const int g = tid >> 4, c = tid & 15;
    const float* wsrc[5] = { nc0w, nc1w, nc2w, ec0w, ec1w };
    const float* bsrc[5] = { nc0b, nc1b, nc2b, ec0b, ec1b };
    const int hbase[5] = { 0, 12, 17, 21, 26 };
    const int hlen[5]  = { 12, 5, 4, 5, 4 };
    for (int hh = 0; hh < 5; ++hh)
      for (int r = 0; r < hlen[hh]; ++r)
        for (int col = tid; col < H; col += 256)
          S.c.cw[(hbase[hh] + r) * H + col] = wsrc[hh][r * H + col];
    if (tid < 30) {
      const int hh = tid < 12 ? 0 : tid < 17 ? 1 : tid < 21 ? 2 : tid < 26 ? 3 : 4;
      S.c.cb[tid] = bsrc[hh][tid - hbase[hh]];
    }
    __syncthreads();

    int m = 1;
    bool done = false;
    for (int i = 0; i < MAXN; ++i) {
      float npmax[3]; int nidx[3];
      bool is_end = false, andacc = true;
      for (int t = -1; t < i; ++t) {
        S.c.hc[tid] = spin2f(&ws->hP[m][tid], &ws->hS[m][tid], sc);
        __syncthreads();
        for (int rsel = 0; rsel < 2; ++rsel) {
          const int r = g + 16 * rsel;
          float p = 0.f;
          if (r < 30) {
            #pragma unroll
            for (int it = 0; it < 16; ++it) {
              const int col = c + 16 * it;
              p += S.c.cw[r * H + col] * S.c.hc[col];
            }
          }
          for (int off = 1; off < 16; off <<= 1) p += __shfl_xor(p, off);
          if (r < 30 && c == 0) S.c.logits[r] = p + S.c.cb[r];
        }
        __syncthreads();
        if (tid < 5) {
          const int base = hbase[tid], len = hlen[tid];
          float best = S.c.logits[base]; int bi = 0;
          for (int j = 1; j < len; ++j) {
            const float l = S.c.logits[base + j];
            if (l > best) { best = l; bi = j; }
          }
          float s = 0.f;
          for (int j = 0; j < len; ++j) s += expf(S.c.logits[base + j] - best);
          S.c.resp[tid] = 1.0f / s;
          S.c.resi[tid] = bi;
        }
        __syncthreads();
        if (t < 0) {
          npmax[0] = S.c.resp[0]; npmax[1] = S.c.resp[1]; npmax[2] = S.c.resp[2];
          nidx[0] = S.c.resi[0]; nidx[1] = S.c.resi[1]; nidx[2] = S.c.resi[2];
          is_end = (S.c.resi[0] == 11);            // END_NODE
          if (i == 0 && tid == 0) {                // i=0: ei_t[0] = classify(h1)
            S.c.ept[0][0] = S.c.resp[3]; S.c.ept[0][1] = S.c.resp[4];
            S.c.eit[0][0] = S.c.resi[3]; S.c.eit[0][1] = S.c.resi[4];
          }
        } else {
          if (tid == 0) {
            S.c.ept[t][0] = S.c.resp[3]; S.c.ept[t][1] = S.c.resp[4];
            S.c.eit[t][0] = S.c.resi[3]; S.c.eit[t][1] = S.c.resi[4];
          }
          andacc = andacc && (S.c.resi[3] == 0);
        }
        __syncthreads();
        ++m;
      }
      const bool no_edges = (i > 0) && andacc;
      const bool active = !done;
      const bool node_ok = active && !is_end && !no_edges;
      if (tid == 0) {
        const u32 d = 1u | (is_end ? 2u : 0u) | (no_edges ? 4u : 0u);
        pub2(&ws->decP[i], &ws->decS[i], d, sc);
      }
      if (tid < MAXN) {
        const int j = tid;
        const bool vj = j < i;
        const bool ev = vj && node_ok && (i > 0);
        const int tt = vj ? (i - 1 - j) : 0;
        out[EP_OFF + (i * MAXN + j) * 2 + 0] = ev ? S.c.ept[tt][0] : 0.f;
        out[EP_OFF + (i * MAXN + j) * 2 + 1] = ev ? S.c.ept[tt][1] : 0.f;
        out[EI_OFF + (i * MAXN + j) * 2 + 0] = (float)S.c.eit[tt][0];
        out[EI_OFF + (i * MAXN + j) * 2 + 1] = (float)S.c.eit[tt][1];
        out[EV_OFF + i * MAXN + j] = ev ? 1.f : 0.f;
      } else if (tid < MAXN + 8) {
        const int q = tid - MAXN;
        if (q < 3)       out[NP_OFF + i * 3 + q]       = node_ok ? npmax[q] : 0.f;
        else if (q < 6)  out[NI_OFF + i * 3 + (q - 3)] = (float)nidx[q - 3];
        else if (q == 6) out[NV_OFF + i]               = node_ok ? 1.f : 0.f;
      }
      done = done || is_end || no_edges;
      __syncthreads();
    }

  } else {
    // =================== Gi HELPERS (agent domain) ===================
    const int e = bid - WG_HELP0;               // 0..11
    const bool is_edge = (e < NHELP_PER);
    const int rowbase = (e % NHELP_PER) * 128;
    const float* Wih = is_edge ? eWih : nWih;
    float* gdst = is_edge ? &ws->gi_e[0][0] : &ws->gi_n[0][0];
    const int g = tid >> 4, c = tid & 15;
    int m_node = 1;
    for (int i = 0; i < MAXN; ++i) {
      S.hp.h1[tid] = spinf(&ws->hS[m_node][tid]);
      __syncthreads();
      for (int rr = 0; rr < 8; ++rr) {
        const int row = rowbase + g * 8 + rr;
        float p = 0.f;
        #pragma unroll
        for (int u = 0; u < 4; ++u) {
          const float4 wv = *(const float4*)&Wih[row * H + c * 16 + u * 4];
          p += wv.x * S.hp.h1[c * 16 + u * 4 + 0]
             + wv.y * S.hp.h1[c * 16 + u * 4 + 1]
             + wv.z * S.hp.h1[c * 16 + u * 4 + 2]
             + wv.w * S.hp.h1[c * 16 + u * 4 + 3];
        }
        for (int off = 1; off < 16; off <<= 1) p += __shfl_xor(p, off);
        if (c == 0) pubf(&gdst[i * G3 + row], p);
      }
      __syncthreads();
      m_node += 1 + i;
    }
  }
}

extern "C" void kernel_launch(void* const* d_in, const int* in_sizes, int n_in,
                              void* d_out, int out_size, void* d_ws, size_t ws_size,
                              hipStream_t stream) {
  // sentinel-fill comm region (incl. winner); zero the election tickets
  hipMemsetAsync(d_ws, 0xFF, offsetof(Wksp, ticket), stream);
  hipMemsetAsync((char*)d_ws + offsetof(Wksp, ticket), 0,
                 sizeof(Wksp) - offsetof(Wksp, ticket), stream);
  Generator_34746285425383_kernel<<<dim3(NWG), dim3(256), 0, stream>>>(
      (const float*)d_in[0],  (const float*)d_in[1],  (const float*)d_in[2],
      (const float*)d_in[3],  (const float*)d_in[4],  (const float*)d_in[5],
      (const float*)d_in[6],  (const float*)d_in[7],  (const float*)d_in[8],
      (const float*)d_in[9],  (const float*)d_in[10],
      (const float*)d_in[11], (const float*)d_in[12],
      (const float*)d_in[13], (const float*)d_in[14],
      (const float*)d_in[15], (const float*)d_in[16],
      (const float*)d_in[17], (const float*)d_in[18],
      (const float*)d_in[19], (const float*)d_in[20],
      (float*)d_out, (Wksp*)d_ws);
}

// Round 9
// 5048.272 us; speedup vs baseline: 1.6434x; 1.0449x over previous
//
#include <hip/hip_runtime.h>
#include <stdint.h>
#include <cstddef>

// ---------------------------------------------------------------------------
// GraphRNN-style generator. 2081 strictly-sequential GRU states across
// 16 worker WGs (h sliced 16 elems, Whh LDS-resident), 1 classifier WG,
// 12 helper WGs (speculative Wih@h1). R9 = R8 base (passed, sc-mode proven:
// FETCH 13.9->4.2MB) + classifier de-serialization:
//  - lane-parallel head reduce on wave 0 (8/16-lane groups, shfl_xor
//    argmax-first + parallel expf) replaces the tid<5 serial loop,
//  - 2 barriers/state (parity-buffered hc, wave-0 stash, no trailing bar),
//  - boundary no_edges via one wave-0 __ballot over stashed eit,
//  - workers: gi restricted to lanes c<2; publish split c0=primary/c1=shadow,
//  - helpers: s_sleep backoff polls.
// Comm protocol unchanged from R8 (proven): primary sc0 (XCD L2) + agent
// shadow at different address; capped sc0 polls -> agent fallback.
// Sentinel 0xFFFFFFFF (unreachable from finite f32 math), write-once words.
// ---------------------------------------------------------------------------

typedef unsigned int u32;

#define H 256
#define HL 128
#define G3 768
#define NW 16
#define SL 16
#define MAXN 64
#define NSTATE (1 + MAXN + (MAXN*(MAXN-1))/2)   // 2081
#define SENTU 0xFFFFFFFFu
#define DEADV 0x0000DEADu
#define PAD 264

#define WG_CLS NW                   // role 16
#define WG_HELP0 (NW+1)             // roles 17..28
#define NHELP_PER 6
#define NROLE (WG_HELP0 + 2*NHELP_PER) // 29  (<= 32 CUs per XCD)
#define NWG 256                     // 1 WG/CU (LDS-forced); election picks 29

// output layout (f32 words), total 20928
#define NP_OFF 0
#define NI_OFF 192
#define NV_OFF 384
#define EP_OFF 448
#define EI_OFF (EP_OFF + MAXN*MAXN*2)   // 8640
#define EV_OFF (EI_OFF + MAXN*MAXN*2)   // 16832

struct Wksp {
  float hP[NSTATE][H];         // primary h copies (sc0 domain)
  float hS[NSTATE][H];         // shadow h copies (agent domain)
  float gi_e[MAXN][G3];        // eWih @ h1_i (agent domain)
  float gi_n[MAXN][G3];        // nWih @ h1_i
  u32 decP[MAXN];              // primary dec
  u32 decS[MAXN];              // shadow dec
  u32 winner;                  // 0xFF-init; xcd id or DEADV
  u32 padw[7];
  // ---- zero-initialized region below ----
  u32 ticket[8];               // per-XCD election counters
};

union Shm {
  struct {
    float whe[3*SL*PAD];
    float whn[3*SL*PAD];
    float hcur[2][H];          // parity-double-buffered gathered state
    float bihe[3*SL], bhhe[3*SL], bihn[3*SL], bhhn[3*SL];
    float zv[HL];
    u32 dec;
  } w;
  struct {
    float cw[30*H];
    float cb[30];
    float hc[2][H];            // parity-double-buffered gathered state
    float logits[32];
    float np[3]; int ni[3];
    float ept[MAXN][2];
    int   eit[MAXN][2];
    u32 isend, bflag;
  } c;
  struct { float h1[H]; } hp;
};

// ---- primitives -----------------------------------------------------------
__device__ __forceinline__ u32 ld_sc0(const u32* p) {
  u32 v;
  asm volatile("global_load_dword %0, %1, off sc0\n\ts_waitcnt vmcnt(0)"
               : "=&v"(v) : "v"(p) : "memory");
  return v;
}
__device__ __forceinline__ void st_sc0(u32* p, u32 v) {
  asm volatile("global_store_dword %0, %1, off sc0" :: "v"(p), "v"(v) : "memory");
}
__device__ __forceinline__ u32 ld_ag(const u32* p) {
  return __hip_atomic_load(p, __ATOMIC_RELAXED, __HIP_MEMORY_SCOPE_AGENT);
}
__device__ __forceinline__ void st_ag(u32* p, u32 v) {
  __hip_atomic_store(p, v, __ATOMIC_RELAXED, __HIP_MEMORY_SCOPE_AGENT);
}
__device__ __forceinline__ void pub2(u32* pp, u32* sp, u32 v, bool sc) {
  if (sc) st_sc0(pp, v);
  st_ag(sp, v);
}
// consume: capped sc0 polls on primary, then guaranteed agent spin on shadow
__device__ __forceinline__ u32 spin2(const u32* pp, const u32* sp, bool sc) {
  if (sc) {
    #pragma unroll 1
    for (int i = 0; i < 16; ++i) {
      const u32 v = ld_sc0(pp);
      if (v != SENTU) return v;
    }
  }
  u32 v = ld_ag(sp);
  while (v == SENTU) v = ld_ag(sp);
  return v;
}
__device__ __forceinline__ float spin2f(const float* pp, const float* sp, bool sc) {
  return __uint_as_float(spin2((const u32*)pp, (const u32*)sp, sc));
}
// agent-only helpers (gi path, helper WGs)
__device__ __forceinline__ float spinf(const float* p) {
  u32 v = ld_ag((const u32*)p);
  while (v == SENTU) v = ld_ag((const u32*)p);
  return __uint_as_float(v);
}
__device__ __forceinline__ float spinf_slow(const float* p) {
  u32 v = ld_ag((const u32*)p);
  while (v == SENTU) {
    __builtin_amdgcn_s_sleep(1);
    v = ld_ag((const u32*)p);
  }
  return __uint_as_float(v);
}
__device__ __forceinline__ void pubf(float* p, float x) { st_ag((u32*)p, __float_as_uint(x)); }
__device__ __forceinline__ float sigm(float x) { return 1.0f / (1.0f + expf(-x)); }

__global__ __launch_bounds__(256)
void Generator_34746285425383_kernel(
    const float* __restrict__ z, const float* __restrict__ lp_w, const float* __restrict__ lp_b,
    const float* __restrict__ nWih, const float* __restrict__ nWhh,
    const float* __restrict__ nbih, const float* __restrict__ nbhh,
    const float* __restrict__ eWih, const float* __restrict__ eWhh,
    const float* __restrict__ ebih, const float* __restrict__ ebhh,
    const float* __restrict__ nc0w, const float* __restrict__ nc0b,
    const float* __restrict__ nc1w, const float* __restrict__ nc1b,
    const float* __restrict__ nc2w, const float* __restrict__ nc2b,
    const float* __restrict__ ec0w, const float* __restrict__ ec0b,
    const float* __restrict__ ec1w, const float* __restrict__ ec1b,
    float* __restrict__ out, Wksp* __restrict__ ws)
{
  __shared__ Shm S;
  __shared__ int role_s, mode_s;
  const int tid = threadIdx.x;

  // ---------------- election (R6/R8-proven): 29 roles on ONE XCD ----------
  if (tid == 0) {
    u32 xcc;
    asm volatile("s_getreg_b32 %0, hwreg(HW_REG_XCC_ID)" : "=s"(xcc));
    xcc &= 7u;
    const u32 slot = __hip_atomic_fetch_add(&ws->ticket[xcc], 1u,
                        __ATOMIC_RELAXED, __HIP_MEMORY_SCOPE_AGENT);
    if (slot == NROLE - 1) {
      u32 exp = SENTU;
      __hip_atomic_compare_exchange_strong(&ws->winner, &exp, xcc,
          __ATOMIC_RELAXED, __ATOMIC_RELAXED, __HIP_MEMORY_SCOPE_AGENT);
    }
    u32 wv = ld_ag(&ws->winner);
    int iters = 0;
    while (wv == SENTU) {
      ++iters;
      if (iters > 1500 && blockIdx.x == 0) {
        u32 exp = SENTU;
        __hip_atomic_compare_exchange_strong(&ws->winner, &exp, DEADV,
            __ATOMIC_RELAXED, __ATOMIC_RELAXED, __HIP_MEMORY_SCOPE_AGENT);
      }
      wv = ld_ag(&ws->winner);
    }
    if (wv <= 7u) { role_s = (wv == xcc && slot < NROLE) ? (int)slot : -1; mode_s = 1; }
    else          { role_s = ((int)blockIdx.x < NROLE) ? (int)blockIdx.x : -1; mode_s = 0; }
  }
  __syncthreads();
  const int bid = role_s;
  const bool sc = (mode_s != 0);
  if (bid < 0) return;

  if (bid < NW) {
    // =================== WORKER ===================
    const int w = bid, g = tid >> 4, c = tid & 15;
    const int k = w * SL + g;
    const bool gl = (c < 2);                // only lanes whose hp is live
    for (int r = 0; r < 3 * SL; ++r) {
      const int gate = r / SL, gg = r % SL;
      const int grow = gate * H + (w * SL + gg);
      for (int col = tid; col < H; col += 256) {
        S.w.whe[r * PAD + col] = eWhh[grow * H + col];
        S.w.whn[r * PAD + col] = nWhh[grow * H + col];
      }
    }
    if (tid < 3 * SL) {
      const int gate = tid / SL, gg = tid % SL;
      const int grow = gate * H + w * SL + gg;
      S.w.bihe[tid] = ebih[grow]; S.w.bhhe[tid] = ebhh[grow];
      S.w.bihn[tid] = nbih[grow]; S.w.bhhn[tid] = nbhh[grow];
    }
    if (tid < HL) S.w.zv[tid] = z[tid];
    __syncthreads();

    // state 0: h0 = z @ lp_w.T + lp_b
    {
      float p = 0.f;
      for (int it = 0; it < 8; ++it) {
        const int col = c + 16 * it;
        p += S.w.zv[col] * lp_w[k * HL + col];
      }
      for (int off = 1; off < 16; off <<= 1) p += __shfl_xor(p, off);
      const float h0 = p + lp_b[k];
      if (c == 0 && sc) st_sc0((u32*)&ws->hP[0][k], __float_as_uint(h0));
      if (c == 1)       st_ag((u32*)&ws->hS[0][k], __float_as_uint(h0));
    }

    int m = 1, idx_carry = 0;
    bool done = false;
    unsigned long long valid = 0ull;
    float pg0 = 0.f, pg1 = 0.f, pg2 = 0.f;
    const float* pga = nullptr;

    for (int i = 0; i < MAXN; ++i) {
      for (int t = -1; t < i; ++t) {        // t=-1: node step, t>=0: edge steps
        const bool is_node = (t < 0);
        const int hidx = is_node ? idx_carry : (m - 1);
        const int src  = is_node ? (i - 1) : (i - 1 - t);
        float* hc = S.w.hcur[m & 1];
        hc[tid] = spin2f(&ws->hP[hidx][tid], &ws->hS[hidx][tid], sc);
        // x-side (lanes c<2 only; others' hp is dead)
        float gi0 = 0.f, gi1 = 0.f, gi2 = 0.f;
        const bool use_gi = (src >= 0) && ((valid >> src) & 1ull);
        if (gl && use_gi) {
          gi0 = pg0; gi1 = pg1; gi2 = pg2;
          if (__float_as_uint(gi0) == SENTU) gi0 = spinf(&pga[0 * H + k]);
          if (__float_as_uint(gi1) == SENTU) gi1 = spinf(&pga[1 * H + k]);
          if (__float_as_uint(gi2) == SENTU) gi2 = spinf(&pga[2 * H + k]);
        }
        __syncthreads();                    // the ONE barrier per state
        const float* Wl = is_node ? S.w.whn : S.w.whe;
        float p0 = 0.f, p1 = 0.f, p2 = 0.f;
        #pragma unroll
        for (int it = 0; it < 16; ++it) {
          const int col = c + 16 * it;
          const float hv = hc[col];
          p0 += Wl[(0 * SL + g) * PAD + col] * hv;
          p1 += Wl[(1 * SL + g) * PAD + col] * hv;
          p2 += Wl[(2 * SL + g) * PAD + col] * hv;
        }
        for (int off = 1; off < 16; off <<= 1) {
          p0 += __shfl_xor(p0, off);
          p1 += __shfl_xor(p1, off);
          p2 += __shfl_xor(p2, off);
        }
        const float* bih = is_node ? S.w.bihn : S.w.bihe;
        const float* bhh = is_node ? S.w.bhhn : S.w.bhhe;
        const float rr = sigm(gi0 + bih[0 * SL + g] + p0 + bhh[0 * SL + g]);
        const float zz = sigm(gi1 + bih[1 * SL + g] + p1 + bhh[1 * SL + g]);
        const float nn = tanhf(gi2 + bih[2 * SL + g] + rr * (p2 + bhh[2 * SL + g]));
        const float hp = (1.f - zz) * nn + zz * hc[k];
        if (c == 0 && sc) st_sc0((u32*)&ws->hP[m][k], __float_as_uint(hp));
        if (c == 1)       st_ag((u32*)&ws->hS[m][k], __float_as_uint(hp));
        // prefetch next state's gi words (lanes c<2 only)
        if (gl) {
          int ni = i, nt = t + 1;
          if (nt >= i) { ni = i + 1; nt = -1; }
          if (ni < MAXN) {
            const bool nnode = (nt < 0);
            const int nsrc = nnode ? (ni - 1) : (ni - 1 - nt);
            if (nsrc >= 0) {
              pga = nnode ? ws->gi_n[nsrc] : ws->gi_e[nsrc];
              pg0 = __builtin_nontemporal_load(&pga[0 * H + k]);
              pg1 = __builtin_nontemporal_load(&pga[1 * H + k]);
              pg2 = __builtin_nontemporal_load(&pga[2 * H + k]);
            }
          }
        }
        ++m;                                // parity buffers: no trailing barrier
      }
      // boundary: consume classifier decision
      if (tid == 0) S.w.dec = spin2(&ws->decP[i], &ws->decS[i], sc);
      __syncthreads();
      const u32 dec = S.w.dec;
      const bool is_end   = (dec >> 1) & 1u;
      const bool no_edges = (dec >> 2) & 1u;
      const bool active   = !done;
      const bool node_ok  = active && !is_end && !no_edges;
      if (node_ok) valid |= (1ull << i);
      const int s_end = m - 1, node_m = m - 1 - i;
      if (active) idx_carry = (node_ok && i > 0) ? s_end : node_m;
      done = done || is_end || no_edges;
    }

  } else if (bid == WG_CLS) {
    // =================== CLASSIFIER (de-serialized) ===================
    const int g = tid >> 4, c = tid & 15;
    const float* wsrc[5] = { nc0w, nc1w, nc2w, ec0w, ec1w };
    const float* bsrc[5] = { nc0b, nc1b, nc2b, ec0b, ec1b };
    const int hbase[5] = { 0, 12, 17, 21, 26 };
    const int hlen[5]  = { 12, 5, 4, 5, 4 };
    for (int hh = 0; hh < 5; ++hh)
      for (int r = 0; r < hlen[hh]; ++r)
        for (int col = tid; col < H; col += 256)
          S.c.cw[(hbase[hh] + r) * H + col] = wsrc[hh][r * H + col];
    if (tid < 30) {
      const int hh = tid < 12 ? 0 : tid < 17 ? 1 : tid < 21 ? 2 : tid < 26 ? 3 : 4;
      S.c.cb[tid] = bsrc[hh][tid - hbase[hh]];
    }
    __syncthreads();

    int m = 1;
    bool done = false;
    for (int i = 0; i < MAXN; ++i) {
      for (int t = -1; t < i; ++t) {
        float* hcb = S.c.hc[m & 1];
        hcb[tid] = spin2f(&ws->hP[m][tid], &ws->hS[m][tid], sc);
        __syncthreads();                    // B1: hcb ready
        // logits: rows r = g + 16*rsel, 16 lanes/row over 16-col strides
        for (int rsel = 0; rsel < 2; ++rsel) {
          const int r = g + 16 * rsel;
          float p = 0.f;
          if (r < 30) {
            #pragma unroll
            for (int it = 0; it < 16; ++it) {
              const int col = c + 16 * it;
              p += S.c.cw[r * H + col] * hcb[col];
            }
          }
          for (int off = 1; off < 16; off <<= 1) p += __shfl_xor(p, off);
          if (r < 30 && c == 0) S.c.logits[r] = p + S.c.cb[r];
        }
        __syncthreads();                    // B2: logits ready
        // wave-0 lane-parallel head reduce + stash (no further barrier)
        if (tid < 64) {
          const int lane = tid;
          int hh, j;
          if (lane < 16)      { hh = 0; j = lane;      }
          else if (lane < 24) { hh = 1; j = lane - 16; }
          else if (lane < 32) { hh = 2; j = lane - 24; }
          else if (lane < 40) { hh = 3; j = lane - 32; }
          else if (lane < 48) { hh = 4; j = lane - 40; }
          else                { hh = 4; j = 99; }      // dead padding lanes
          const int hb = hbase[hh], hl = hlen[hh];
          const bool live = (j < hl);
          const float myl = live ? S.c.logits[hb + j] : -3.4e38f;
          float mx = myl; int idx = live ? j : 1000;
          #pragma unroll
          for (int mk = 1; mk <= 4; mk <<= 1) {
            const float lv = __shfl_xor(mx, mk);
            const int   iv = __shfl_xor(idx, mk);
            if (lv > mx || (lv == mx && iv < idx)) { mx = lv; idx = iv; }
          }
          { const float lv = __shfl_xor(mx, 8);
            const int   iv = __shfl_xor(idx, 8);
            if (lane < 16 && (lv > mx || (lv == mx && iv < idx))) { mx = lv; idx = iv; } }
          float e = live ? expf(myl - mx) : 0.f;
          #pragma unroll
          for (int mk = 1; mk <= 4; mk <<= 1) e += __shfl_xor(e, mk);
          { const float ev = __shfl_xor(e, 8); if (lane < 16) e += ev; }
          const float pm = 1.0f / e;
          if (t < 0) {
            if (lane == 0)  { S.c.np[0] = pm; S.c.ni[0] = idx;
                              S.c.isend = (idx == 11) ? 1u : 0u; }   // END_NODE
            if (lane == 16) { S.c.np[1] = pm; S.c.ni[1] = idx; }
            if (lane == 24) { S.c.np[2] = pm; S.c.ni[2] = idx; }
            if (i == 0) {                    // i=0: ei_t[0] = classify(h1)
              if (lane == 32) { S.c.ept[0][0] = pm; S.c.eit[0][0] = idx; }
              if (lane == 40) { S.c.ept[0][1] = pm; S.c.eit[0][1] = idx; }
            }
          } else {
            if (lane == 32) { S.c.ept[t][0] = pm; S.c.eit[t][0] = idx; }
            if (lane == 40) { S.c.ept[t][1] = pm; S.c.eit[t][1] = idx; }
          }
        }
        ++m;                                // parity hc: waves 1-3 run ahead
      }
      // ---- round boundary ----
      __syncthreads();                      // stash visible
      if (tid < 64) {
        const bool myok = (tid < i) ? (S.c.eit[tid][0] == 0) : true;
        const unsigned long long b = __ballot(myok);
        if (tid == 0) S.c.bflag = ((b == ~0ull) && (i > 0)) ? 1u : 0u;
      }
      __syncthreads();
      const bool is_end   = (S.c.isend != 0u);
      const bool no_edges = (S.c.bflag != 0u);
      const bool active   = !done;
      const bool node_ok  = active && !is_end && !no_edges;
      if (tid == 0) {
        const u32 d = 1u | (is_end ? 2u : 0u) | (no_edges ? 4u : 0u);
        pub2(&ws->decP[i], &ws->decS[i], d, sc);
      }
      if (tid < MAXN) {
        const int j = tid;
        const bool vj = j < i;
        const bool ev = vj && node_ok && (i > 0);
        const int tt = vj ? (i - 1 - j) : 0;
        out[EP_OFF + (i * MAXN + j) * 2 + 0] = ev ? S.c.ept[tt][0] : 0.f;
        out[EP_OFF + (i * MAXN + j) * 2 + 1] = ev ? S.c.ept[tt][1] : 0.f;
        out[EI_OFF + (i * MAXN + j) * 2 + 0] = (float)S.c.eit[tt][0];
        out[EI_OFF + (i * MAXN + j) * 2 + 1] = (float)S.c.eit[tt][1];
        out[EV_OFF + i * MAXN + j] = ev ? 1.f : 0.f;
      } else if (tid < MAXN + 8) {
        const int q = tid - MAXN;
        if (q < 3)       out[NP_OFF + i * 3 + q]       = node_ok ? S.c.np[q] : 0.f;
        else if (q < 6)  out[NI_OFF + i * 3 + (q - 3)] = (float)S.c.ni[q - 3];
        else if (q == 6) out[NV_OFF + i]               = node_ok ? 1.f : 0.f;
      }
      done = done || is_end || no_edges;
      __syncthreads();                      // protect stash reuse next round
    }

  } else {
    // =================== Gi HELPERS (agent domain, backoff) ===================
    const int e = bid - WG_HELP0;               // 0..11
    const bool is_edge = (e < NHELP_PER);
    const int rowbase = (e % NHELP_PER) * 128;
    const float* Wih = is_edge ? eWih : nWih;
    float* gdst = is_edge ? &ws->gi_e[0][0] : &ws->gi_n[0][0];
    const int g = tid >> 4, c = tid & 15;
    int m_node = 1;
    for (int i = 0; i < MAXN; ++i) {
      S.hp.h1[tid] = spinf_slow(&ws->hS[m_node][tid]);
      __syncthreads();
      for (int rr = 0; rr < 8; ++rr) {
        const int row = rowbase + g * 8 + rr;
        float p = 0.f;
        #pragma unroll
        for (int u = 0; u < 4; ++u) {
          const float4 wv = *(const float4*)&Wih[row * H + c * 16 + u * 4];
          p += wv.x * S.hp.h1[c * 16 + u * 4 + 0]
             + wv.y * S.hp.h1[c * 16 + u * 4 + 1]
             + wv.z * S.hp.h1[c * 16 + u * 4 + 2]
             + wv.w * S.hp.h1[c * 16 + u * 4 + 3];
        }
        for (int off = 1; off < 16; off <<= 1) p += __shfl_xor(p, off);
        if (c == 0) pubf(&gdst[i * G3 + row], p);
      }
      __syncthreads();
      m_node += 1 + i;
    }
  }
}

extern "C" void kernel_launch(void* const* d_in, const int* in_sizes, int n_in,
                              void* d_out, int out_size, void* d_ws, size_t ws_size,
                              hipStream_t stream) {
  // sentinel-fill comm region (incl. winner); zero the election tickets
  hipMemsetAsync(d_ws, 0xFF, offsetof(Wksp, ticket), stream);
  hipMemsetAsync((char*)d_ws + offsetof(Wksp, ticket), 0,
                 sizeof(Wksp) - offsetof(Wksp, ticket), stream);
  Generator_34746285425383_kernel<<<dim3(NWG), dim3(256), 0, stream>>>(
      (const float*)d_in[0],  (const float*)d_in[1],  (const float*)d_in[2],
      (const float*)d_in[3],  (const float*)d_in[4],  (const float*)d_in[5],
      (const float*)d_in[6],  (const float*)d_in[7],  (const float*)d_in[8],
      (const float*)d_in[9],  (const float*)d_in[10],
      (const float*)d_in[11], (const float*)d_in[12],
      (const float*)d_in[13], (const float*)d_in[14],
      (const float*)d_in[15], (const float*)d_in[16],
      (const float*)d_in[17], (const float*)d_in[18],
      (const float*)d_in[19], (const float*)d_in[20],
      (float*)d_out, (Wksp*)d_ws);
}

// Round 10
// 4579.015 us; speedup vs baseline: 1.8118x; 1.1025x over previous
//
#include <hip/hip_runtime.h>
#include <stdint.h>
#include <cstddef>

// ---------------------------------------------------------------------------
// GraphRNN-style generator. 2081 strictly-sequential GRU states across
// 16 worker WGs (h sliced 16 elems), 1 classifier WG, 12 helper WGs.
// R10 = R9 base (passed) with the per-state matvec moved OFF the LDS unit:
//  - each worker thread keeps its 96 loop-invariant Whh weights (3 gates x
//    16 cols x {node,edge}) in VGPRs; matvec = 96 reg FMAs + 16 hc LDS reads.
//    FP summation order identical to R9 (same cols, same order, same butterfly)
//    -> numerics bit-identical to the passing kernel.
//  - classifier rows likewise in registers (32 floats/thread).
//  - LDS W tiles deleted; a force-pad keeps LDS ~104KB -> still 1 WG/CU.
// Comm protocol unchanged (R8-proven): primary sc0 (XCD L2) + agent shadow,
// capped sc0 polls -> agent fallback; XCD election with dead-man fallback.
// Sentinel 0xFFFFFFFF (unreachable from finite f32 math), write-once words.
// ---------------------------------------------------------------------------

typedef unsigned int u32;

#define H 256
#define HL 128
#define G3 768
#define NW 16
#define SL 16
#define MAXN 64
#define NSTATE (1 + MAXN + (MAXN*(MAXN-1))/2)   // 2081
#define SENTU 0xFFFFFFFFu
#define DEADV 0x0000DEADu

#define WG_CLS NW                   // role 16
#define WG_HELP0 (NW+1)             // roles 17..28
#define NHELP_PER 6
#define NROLE (WG_HELP0 + 2*NHELP_PER) // 29  (<= 32 CUs per XCD)
#define NWG 256                     // 1 WG/CU (LDS-forced); election picks 29

// output layout (f32 words), total 20928
#define NP_OFF 0
#define NI_OFF 192
#define NV_OFF 384
#define EP_OFF 448
#define EI_OFF (EP_OFF + MAXN*MAXN*2)   // 8640
#define EV_OFF (EI_OFF + MAXN*MAXN*2)   // 16832

struct Wksp {
  float hP[NSTATE][H];         // primary h copies (sc0 domain)
  float hS[NSTATE][H];         // shadow h copies (agent domain)
  float gi_e[MAXN][G3];        // eWih @ h1_i (agent domain)
  float gi_n[MAXN][G3];        // nWih @ h1_i
  u32 decP[MAXN];              // primary dec
  u32 decS[MAXN];              // shadow dec
  u32 winner;                  // 0xFF-init; xcd id or DEADV
  u32 padw[7];
  // ---- zero-initialized region below ----
  u32 ticket[8];               // per-XCD election counters
};

union Shm {
  float force[26624];          // 104KB: keep 1 WG/CU
  struct {
    float hcur[2][H];          // parity-double-buffered gathered state
    float bihe[3*SL], bhhe[3*SL], bihn[3*SL], bhhn[3*SL];
    float zv[HL];
    u32 dec;
  } w;
  struct {
    float cb[30];
    float hc[2][H];            // parity-double-buffered gathered state
    float logits[32];
    float np[3]; int ni[3];
    float ept[MAXN][2];
    int   eit[MAXN][2];
    u32 isend, bflag;
  } c;
  struct { float h1[H]; } hp;
};

// ---- primitives -----------------------------------------------------------
__device__ __forceinline__ u32 ld_sc0(const u32* p) {
  u32 v;
  asm volatile("global_load_dword %0, %1, off sc0\n\ts_waitcnt vmcnt(0)"
               : "=&v"(v) : "v"(p) : "memory");
  return v;
}
__device__ __forceinline__ void st_sc0(u32* p, u32 v) {
  asm volatile("global_store_dword %0, %1, off sc0" :: "v"(p), "v"(v) : "memory");
}
__device__ __forceinline__ u32 ld_ag(const u32* p) {
  return __hip_atomic_load(p, __ATOMIC_RELAXED, __HIP_MEMORY_SCOPE_AGENT);
}
__device__ __forceinline__ void st_ag(u32* p, u32 v) {
  __hip_atomic_store(p, v, __ATOMIC_RELAXED, __HIP_MEMORY_SCOPE_AGENT);
}
__device__ __forceinline__ void pub2(u32* pp, u32* sp, u32 v, bool sc) {
  if (sc) st_sc0(pp, v);
  st_ag(sp, v);
}
// consume: capped sc0 polls on primary, then guaranteed agent spin on shadow
__device__ __forceinline__ u32 spin2(const u32* pp, const u32* sp, bool sc) {
  if (sc) {
    #pragma unroll 1
    for (int i = 0; i < 16; ++i) {
      const u32 v = ld_sc0(pp);
      if (v != SENTU) return v;
    }
  }
  u32 v = ld_ag(sp);
  while (v == SENTU) v = ld_ag(sp);
  return v;
}
__device__ __forceinline__ float spin2f(const float* pp, const float* sp, bool sc) {
  return __uint_as_float(spin2((const u32*)pp, (const u32*)sp, sc));
}
// agent-only helpers (gi path, helper WGs)
__device__ __forceinline__ float spinf(const float* p) {
  u32 v = ld_ag((const u32*)p);
  while (v == SENTU) v = ld_ag((const u32*)p);
  return __uint_as_float(v);
}
__device__ __forceinline__ float spinf_slow(const float* p) {
  u32 v = ld_ag((const u32*)p);
  while (v == SENTU) {
    __builtin_amdgcn_s_sleep(1);
    v = ld_ag((const u32*)p);
  }
  return __uint_as_float(v);
}
__device__ __forceinline__ void pubf(float* p, float x) { st_ag((u32*)p, __float_as_uint(x)); }
__device__ __forceinline__ float sigm(float x) { return 1.0f / (1.0f + expf(-x)); }

__global__ __launch_bounds__(256, 1)
void Generator_34746285425383_kernel(
    const float* __restrict__ z, const float* __restrict__ lp_w, const float* __restrict__ lp_b,
    const float* __restrict__ nWih, const float* __restrict__ nWhh,
    const float* __restrict__ nbih, const float* __restrict__ nbhh,
    const float* __restrict__ eWih, const float* __restrict__ eWhh,
    const float* __restrict__ ebih, const float* __restrict__ ebhh,
    const float* __restrict__ nc0w, const float* __restrict__ nc0b,
    const float* __restrict__ nc1w, const float* __restrict__ nc1b,
    const float* __restrict__ nc2w, const float* __restrict__ nc2b,
    const float* __restrict__ ec0w, const float* __restrict__ ec0b,
    const float* __restrict__ ec1w, const float* __restrict__ ec1b,
    float* __restrict__ out, Wksp* __restrict__ ws)
{
  __shared__ Shm S;
  __shared__ int role_s, mode_s;
  const int tid = threadIdx.x;

  // ---------------- election (R6/R8-proven): 29 roles on ONE XCD ----------
  if (tid == 0) {
    u32 xcc;
    asm volatile("s_getreg_b32 %0, hwreg(HW_REG_XCC_ID)" : "=s"(xcc));
    xcc &= 7u;
    const u32 slot = __hip_atomic_fetch_add(&ws->ticket[xcc], 1u,
                        __ATOMIC_RELAXED, __HIP_MEMORY_SCOPE_AGENT);
    if (slot == NROLE - 1) {
      u32 exp = SENTU;
      __hip_atomic_compare_exchange_strong(&ws->winner, &exp, xcc,
          __ATOMIC_RELAXED, __ATOMIC_RELAXED, __HIP_MEMORY_SCOPE_AGENT);
    }
    u32 wv = ld_ag(&ws->winner);
    int iters = 0;
    while (wv == SENTU) {
      ++iters;
      if (iters > 1500 && blockIdx.x == 0) {
        u32 exp = SENTU;
        __hip_atomic_compare_exchange_strong(&ws->winner, &exp, DEADV,
            __ATOMIC_RELAXED, __ATOMIC_RELAXED, __HIP_MEMORY_SCOPE_AGENT);
      }
      wv = ld_ag(&ws->winner);
    }
    if (wv <= 7u) { role_s = (wv == xcc && slot < NROLE) ? (int)slot : -1; mode_s = 1; }
    else          { role_s = ((int)blockIdx.x < NROLE) ? (int)blockIdx.x : -1; mode_s = 0; }
  }
  __syncthreads();
  const int bid = role_s;
  const bool sc = (mode_s != 0);
  if (bid < 0) return;

  if (bid < NW) {
    // =================== WORKER (register-resident Whh) ===================
    const int w = bid, g = tid >> 4, c = tid & 15;
    const int k = w * SL + g;
    const bool gl = (c < 2);                // only lanes whose hp is live
    // loop-invariant weights -> VGPRs (rows {k, H+k, 2H+k}, cols c+16*it)
    float wn0[16], wn1[16], wn2[16], we0[16], we1[16], we2[16];
    #pragma unroll
    for (int it = 0; it < 16; ++it) {
      const int col = c + 16 * it;
      wn0[it] = nWhh[(0 * H + k) * H + col];
      wn1[it] = nWhh[(1 * H + k) * H + col];
      wn2[it] = nWhh[(2 * H + k) * H + col];
      we0[it] = eWhh[(0 * H + k) * H + col];
      we1[it] = eWhh[(1 * H + k) * H + col];
      we2[it] = eWhh[(2 * H + k) * H + col];
    }
    if (tid < 3 * SL) {
      const int gate = tid / SL, gg = tid % SL;
      const int grow = gate * H + w * SL + gg;
      S.w.bihe[tid] = ebih[grow]; S.w.bhhe[tid] = ebhh[grow];
      S.w.bihn[tid] = nbih[grow]; S.w.bhhn[tid] = nbhh[grow];
    }
    if (tid < HL) S.w.zv[tid] = z[tid];
    __syncthreads();

    // state 0: h0 = z @ lp_w.T + lp_b
    {
      float p = 0.f;
      for (int it = 0; it < 8; ++it) {
        const int col = c + 16 * it;
        p += S.w.zv[col] * lp_w[k * HL + col];
      }
      for (int off = 1; off < 16; off <<= 1) p += __shfl_xor(p, off);
      const float h0 = p + lp_b[k];
      if (c == 0 && sc) st_sc0((u32*)&ws->hP[0][k], __float_as_uint(h0));
      if (c == 1)       st_ag((u32*)&ws->hS[0][k], __float_as_uint(h0));
    }

    int m = 1, idx_carry = 0;
    bool done = false;
    unsigned long long valid = 0ull;
    float pg0 = 0.f, pg1 = 0.f, pg2 = 0.f;
    const float* pga = nullptr;

    for (int i = 0; i < MAXN; ++i) {
      for (int t = -1; t < i; ++t) {        // t=-1: node step, t>=0: edge steps
        const bool is_node = (t < 0);
        const int hidx = is_node ? idx_carry : (m - 1);
        const int src  = is_node ? (i - 1) : (i - 1 - t);
        float* hc = S.w.hcur[m & 1];
        hc[tid] = spin2f(&ws->hP[hidx][tid], &ws->hS[hidx][tid], sc);
        // x-side (lanes c<2 only; others' hp is dead)
        float gi0 = 0.f, gi1 = 0.f, gi2 = 0.f;
        const bool use_gi = (src >= 0) && ((valid >> src) & 1ull);
        if (gl && use_gi) {
          gi0 = pg0; gi1 = pg1; gi2 = pg2;
          if (__float_as_uint(gi0) == SENTU) gi0 = spinf(&pga[0 * H + k]);
          if (__float_as_uint(gi1) == SENTU) gi1 = spinf(&pga[1 * H + k]);
          if (__float_as_uint(gi2) == SENTU) gi2 = spinf(&pga[2 * H + k]);
        }
        __syncthreads();                    // the ONE barrier per state
        // gh = Whh @ h from REGISTERS (same FP order as R9: it ascending)
        float p0 = 0.f, p1 = 0.f, p2 = 0.f;
        if (is_node) {
          #pragma unroll
          for (int it = 0; it < 16; ++it) {
            const float hv = hc[c + 16 * it];
            p0 += wn0[it] * hv; p1 += wn1[it] * hv; p2 += wn2[it] * hv;
          }
        } else {
          #pragma unroll
          for (int it = 0; it < 16; ++it) {
            const float hv = hc[c + 16 * it];
            p0 += we0[it] * hv; p1 += we1[it] * hv; p2 += we2[it] * hv;
          }
        }
        for (int off = 1; off < 16; off <<= 1) {
          p0 += __shfl_xor(p0, off);
          p1 += __shfl_xor(p1, off);
          p2 += __shfl_xor(p2, off);
        }
        const float* bih = is_node ? S.w.bihn : S.w.bihe;
        const float* bhh = is_node ? S.w.bhhn : S.w.bhhe;
        const float rr = sigm(gi0 + bih[0 * SL + g] + p0 + bhh[0 * SL + g]);
        const float zz = sigm(gi1 + bih[1 * SL + g] + p1 + bhh[1 * SL + g]);
        const float nn = tanhf(gi2 + bih[2 * SL + g] + rr * (p2 + bhh[2 * SL + g]));
        const float hp = (1.f - zz) * nn + zz * hc[k];
        if (c == 0 && sc) st_sc0((u32*)&ws->hP[m][k], __float_as_uint(hp));
        if (c == 1)       st_ag((u32*)&ws->hS[m][k], __float_as_uint(hp));
        // prefetch next state's gi words (lanes c<2 only)
        if (gl) {
          int ni = i, nt = t + 1;
          if (nt >= i) { ni = i + 1; nt = -1; }
          if (ni < MAXN) {
            const bool nnode = (nt < 0);
            const int nsrc = nnode ? (ni - 1) : (ni - 1 - nt);
            if (nsrc >= 0) {
              pga = nnode ? ws->gi_n[nsrc] : ws->gi_e[nsrc];
              pg0 = __builtin_nontemporal_load(&pga[0 * H + k]);
              pg1 = __builtin_nontemporal_load(&pga[1 * H + k]);
              pg2 = __builtin_nontemporal_load(&pga[2 * H + k]);
            }
          }
        }
        ++m;                                // parity buffers: no trailing barrier
      }
      // boundary: consume classifier decision
      if (tid == 0) S.w.dec = spin2(&ws->decP[i], &ws->decS[i], sc);
      __syncthreads();
      const u32 dec = S.w.dec;
      const bool is_end   = (dec >> 1) & 1u;
      const bool no_edges = (dec >> 2) & 1u;
      const bool active   = !done;
      const bool node_ok  = active && !is_end && !no_edges;
      if (node_ok) valid |= (1ull << i);
      const int s_end = m - 1, node_m = m - 1 - i;
      if (active) idx_carry = (node_ok && i > 0) ? s_end : node_m;
      done = done || is_end || no_edges;
    }

  } else if (bid == WG_CLS) {
    // =================== CLASSIFIER (register-resident rows) ===============
    const int g = tid >> 4, c = tid & 15;
    const float* wsrc[5] = { nc0w, nc1w, nc2w, ec0w, ec1w };
    const float* bsrc[5] = { nc0b, nc1b, nc2b, ec0b, ec1b };
    const int hbase[5] = { 0, 12, 17, 21, 26 };
    // rows g and g+16 (cols c+16*it) into registers
    float cw0[16], cw1[16];
    {
      const int r0 = g;
      const int h0i = r0 < 12 ? 0 : r0 < 17 ? 1 : r0 < 21 ? 2 : r0 < 26 ? 3 : 4;
      const float* W0 = wsrc[h0i];
      const int rr0 = r0 - hbase[h0i];
      const int r1 = g + 16;
      const int h1i = r1 < 17 ? 1 : r1 < 21 ? 2 : r1 < 26 ? 3 : 4;
      const float* W1 = wsrc[h1i];
      const int rr1 = r1 - hbase[h1i];
      const bool live1 = (r1 < 30);
      #pragma unroll
      for (int it = 0; it < 16; ++it) {
        const int col = c + 16 * it;
        cw0[it] = W0[rr0 * H + col];
        cw1[it] = live1 ? W1[rr1 * H + col] : 0.f;
      }
    }
    if (tid < 30) {
      const int hh = tid < 12 ? 0 : tid < 17 ? 1 : tid < 21 ? 2 : tid < 26 ? 3 : 4;
      S.c.cb[tid] = bsrc[hh][tid - hbase[hh]];
    }
    __syncthreads();

    int m = 1;
    bool done = false;
    for (int i = 0; i < MAXN; ++i) {
      for (int t = -1; t < i; ++t) {
        float* hcb = S.c.hc[m & 1];
        hcb[tid] = spin2f(&ws->hP[m][tid], &ws->hS[m][tid], sc);
        __syncthreads();                    // B1: hcb ready
        // logits from registers (same FP order as R9)
        {
          float p0 = 0.f, p1 = 0.f;
          #pragma unroll
          for (int it = 0; it < 16; ++it) {
            const float hv = hcb[c + 16 * it];
            p0 += cw0[it] * hv;
            p1 += cw1[it] * hv;
          }
          for (int off = 1; off < 16; off <<= 1) {
            p0 += __shfl_xor(p0, off);
            p1 += __shfl_xor(p1, off);
          }
          if (c == 0) {
            S.c.logits[g] = p0 + S.c.cb[g];
            if (g + 16 < 30) S.c.logits[g + 16] = p1 + S.c.cb[g + 16];
          }
        }
        __syncthreads();                    // B2: logits ready
        // wave-0 lane-parallel head reduce + stash (no further barrier)
        if (tid < 64) {
          const int lane = tid;
          int hh, j;
          if (lane < 16)      { hh = 0; j = lane;      }
          else if (lane < 24) { hh = 1; j = lane - 16; }
          else if (lane < 32) { hh = 2; j = lane - 24; }
          else if (lane < 40) { hh = 3; j = lane - 32; }
          else if (lane < 48) { hh = 4; j = lane - 40; }
          else                { hh = 4; j = 99; }      // dead padding lanes
          const int hb = hbase[hh];
          const int hl = hh == 0 ? 12 : hh == 1 ? 5 : hh == 2 ? 4 : hh == 3 ? 5 : 4;
          const bool live = (j < hl);
          const float myl = live ? S.c.logits[hb + j] : -3.4e38f;
          float mx = myl; int idx = live ? j : 1000;
          #pragma unroll
          for (int mk = 1; mk <= 4; mk <<= 1) {
            const float lv = __shfl_xor(mx, mk);
            const int   iv = __shfl_xor(idx, mk);
            if (lv > mx || (lv == mx && iv < idx)) { mx = lv; idx = iv; }
          }
          { const float lv = __shfl_xor(mx, 8);
            const int   iv = __shfl_xor(idx, 8);
            if (lane < 16 && (lv > mx || (lv == mx && iv < idx))) { mx = lv; idx = iv; } }
          float e = live ? expf(myl - mx) : 0.f;
          #pragma unroll
          for (int mk = 1; mk <= 4; mk <<= 1) e += __shfl_xor(e, mk);
          { const float ev = __shfl_xor(e, 8); if (lane < 16) e += ev; }
          const float pm = 1.0f / e;
          if (t < 0) {
            if (lane == 0)  { S.c.np[0] = pm; S.c.ni[0] = idx;
                              S.c.isend = (idx == 11) ? 1u : 0u; }   // END_NODE
            if (lane == 16) { S.c.np[1] = pm; S.c.ni[1] = idx; }
            if (lane == 24) { S.c.np[2] = pm; S.c.ni[2] = idx; }
            if (i == 0) {                    // i=0: ei_t[0] = classify(h1)
              if (lane == 32) { S.c.ept[0][0] = pm; S.c.eit[0][0] = idx; }
              if (lane == 40) { S.c.ept[0][1] = pm; S.c.eit[0][1] = idx; }
            }
          } else {
            if (lane == 32) { S.c.ept[t][0] = pm; S.c.eit[t][0] = idx; }
            if (lane == 40) { S.c.ept[t][1] = pm; S.c.eit[t][1] = idx; }
          }
        }
        ++m;                                // parity hc: waves 1-3 run ahead
      }
      // ---- round boundary ----
      __syncthreads();                      // stash visible
      if (tid < 64) {
        const bool myok = (tid < i) ? (S.c.eit[tid][0] == 0) : true;
        const unsigned long long b = __ballot(myok);
        if (tid == 0) S.c.bflag = ((b == ~0ull) && (i > 0)) ? 1u : 0u;
      }
      __syncthreads();
      const bool is_end   = (S.c.isend != 0u);
      const bool no_edges = (S.c.bflag != 0u);
      const bool active   = !done;
      const bool node_ok  = active && !is_end && !no_edges;
      if (tid == 0) {
        const u32 d = 1u | (is_end ? 2u : 0u) | (no_edges ? 4u : 0u);
        pub2(&ws->decP[i], &ws->decS[i], d, sc);
      }
      if (tid < MAXN) {
        const int j = tid;
        const bool vj = j < i;
        const bool ev = vj && node_ok && (i > 0);
        const int tt = vj ? (i - 1 - j) : 0;
        out[EP_OFF + (i * MAXN + j) * 2 + 0] = ev ? S.c.ept[tt][0] : 0.f;
        out[EP_OFF + (i * MAXN + j) * 2 + 1] = ev ? S.c.ept[tt][1] : 0.f;
        out[EI_OFF + (i * MAXN + j) * 2 + 0] = (float)S.c.eit[tt][0];
        out[EI_OFF + (i * MAXN + j) * 2 + 1] = (float)S.c.eit[tt][1];
        out[EV_OFF + i * MAXN + j] = ev ? 1.f : 0.f;
      } else if (tid < MAXN + 8) {
        const int q = tid - MAXN;
        if (q < 3)       out[NP_OFF + i * 3 + q]       = node_ok ? S.c.np[q] : 0.f;
        else if (q < 6)  out[NI_OFF + i * 3 + (q - 3)] = (float)S.c.ni[q - 3];
        else if (q == 6) out[NV_OFF + i]               = node_ok ? 1.f : 0.f;
      }
      done = done || is_end || no_edges;
      __syncthreads();                      // protect stash reuse next round
    }

  } else {
    // =================== Gi HELPERS (agent domain, backoff) ===================
    const int e = bid - WG_HELP0;               // 0..11
    const bool is_edge = (e < NHELP_PER);
    const int rowbase = (e % NHELP_PER) * 128;
    const float* Wih = is_edge ? eWih : nWih;
    float* gdst = is_edge ? &ws->gi_e[0][0] : &ws->gi_n[0][0];
    const int g = tid >> 4, c = tid & 15;
    int m_node = 1;
    for (int i = 0; i < MAXN; ++i) {
      S.hp.h1[tid] = spinf_slow(&ws->hS[m_node][tid]);
      __syncthreads();
      for (int rr = 0; rr < 8; ++rr) {
        const int row = rowbase + g * 8 + rr;
        float p = 0.f;
        #pragma unroll
        for (int u = 0; u < 4; ++u) {
          const float4 wv = *(const float4*)&Wih[row * H + c * 16 + u * 4];
          p += wv.x * S.hp.h1[c * 16 + u * 4 + 0]
             + wv.y * S.hp.h1[c * 16 + u * 4 + 1]
             + wv.z * S.hp.h1[c * 16 + u * 4 + 2]
             + wv.w * S.hp.h1[c * 16 + u * 4 + 3];
        }
        for (int off = 1; off < 16; off <<= 1) p += __shfl_xor(p, off);
        if (c == 0) pubf(&gdst[i * G3 + row], p);
      }
      __syncthreads();
      m_node += 1 + i;
    }
  }
}

extern "C" void kernel_launch(void* const* d_in, const int* in_sizes, int n_in,
                              void* d_out, int out_size, void* d_ws, size_t ws_size,
                              hipStream_t stream) {
  // sentinel-fill comm region (incl. winner); zero the election tickets
  hipMemsetAsync(d_ws, 0xFF, offsetof(Wksp, ticket), stream);
  hipMemsetAsync((char*)d_ws + offsetof(Wksp, ticket), 0,
                 sizeof(Wksp) - offsetof(Wksp, ticket), stream);
  Generator_34746285425383_kernel<<<dim3(NWG), dim3(256), 0, stream>>>(
      (const float*)d_in[0],  (const float*)d_in[1],  (const float*)d_in[2],
      (const float*)d_in[3],  (const float*)d_in[4],  (const float*)d_in[5],
      (const float*)d_in[6],  (const float*)d_in[7],  (const float*)d_in[8],
      (const float*)d_in[9],  (const float*)d_in[10],
      (const float*)d_in[11], (const float*)d_in[12],
      (const float*)d_in[13], (const float*)d_in[14],
      (const float*)d_in[15], (const float*)d_in[16],
      (const float*)d_in[17], (const float*)d_in[18],
      (const float*)d_in[19], (const float*)d_in[20],
      (float*)d_out, (Wksp*)d_ws);
}